// Round 1
// baseline (1597.555 us; speedup 1.0000x reference)
//
#include <hip/hip_runtime.h>
#include <math.h>

#define NN     4096
#define IND    512
#define HD     64
#define HEADS  4
#define HD1    256
#define NC     10
#define CH     1024
#define BK     16
#define TILE   64

// ---------------- row normalize (mean/std over 512, ddof=1) ----------------
__global__ __launch_bounds__(256) void k_norm(const float* __restrict__ x,
                                              float* __restrict__ y) {
  int row  = blockIdx.x * 4 + (threadIdx.x >> 6);
  int lane = threadIdx.x & 63;
  const float4* src = (const float4*)(x + (size_t)row * IND);
  float4 a = src[lane];
  float4 b = src[lane + 64];
  float s = a.x + a.y + a.z + a.w + b.x + b.y + b.z + b.w;
#pragma unroll
  for (int off = 32; off; off >>= 1) s += __shfl_xor(s, off);
  float mean = s * (1.0f / IND);
  float ssq = 0.f, d;
  d = a.x - mean; ssq += d * d;
  d = a.y - mean; ssq += d * d;
  d = a.z - mean; ssq += d * d;
  d = a.w - mean; ssq += d * d;
  d = b.x - mean; ssq += d * d;
  d = b.y - mean; ssq += d * d;
  d = b.z - mean; ssq += d * d;
  d = b.w - mean; ssq += d * d;
#pragma unroll
  for (int off = 32; off; off >>= 1) ssq += __shfl_xor(ssq, off);
  float inv = 1.0f / (sqrtf(ssq * (1.0f / (IND - 1))) + 1e-9f);
  float4* dst = (float4*)(y + (size_t)row * IND);
  a.x = (a.x - mean) * inv; a.y = (a.y - mean) * inv;
  a.z = (a.z - mean) * inv; a.w = (a.w - mean) * inv;
  b.x = (b.x - mean) * inv; b.y = (b.y - mean) * inv;
  b.z = (b.z - mean) * inv; b.w = (b.w - mean) * inv;
  dst[lane] = a; dst[lane + 64] = b;
}

// ---------- C[M,N] = A[M,K](lda) @ B[N,K](ldb)^T, opt bias, opt col remap ----------
// remap68: out col c -> c + 4*(c>>6)  (injects a 4-col gap after every 64 cols)
__global__ __launch_bounds__(256) void k_gemm_bt(
    const float* __restrict__ A, int lda,
    const float* __restrict__ B, int ldb,
    float* __restrict__ C, int ldc,
    int M, int N, int K,
    const float* __restrict__ bias, int remap68) {
  __shared__ float As[BK][TILE + 4];
  __shared__ float Bs[BK][TILE + 4];
  int tid = threadIdx.x;
  int m0 = blockIdx.x * TILE;
  int n0 = blockIdx.y * TILE;
  int ty = tid >> 4, tx = tid & 15;
  int lr = tid >> 2;
  int lk = (tid & 3) << 2;
  float acc[4][4] = {};
  for (int k0 = 0; k0 < K; k0 += BK) {
    float4 va = *(const float4*)(A + (size_t)(m0 + lr) * lda + k0 + lk);
    As[lk + 0][lr] = va.x; As[lk + 1][lr] = va.y;
    As[lk + 2][lr] = va.z; As[lk + 3][lr] = va.w;
    int bn = n0 + lr;
    float4 vb = make_float4(0.f, 0.f, 0.f, 0.f);
    if (bn < N) vb = *(const float4*)(B + (size_t)bn * ldb + k0 + lk);
    Bs[lk + 0][lr] = vb.x; Bs[lk + 1][lr] = vb.y;
    Bs[lk + 2][lr] = vb.z; Bs[lk + 3][lr] = vb.w;
    __syncthreads();
#pragma unroll
    for (int kk = 0; kk < BK; ++kk) {
      float4 a4 = *(const float4*)&As[kk][ty << 2];
      float4 b4 = *(const float4*)&Bs[kk][tx << 2];
      float ar[4] = {a4.x, a4.y, a4.z, a4.w};
      float br[4] = {b4.x, b4.y, b4.z, b4.w};
#pragma unroll
      for (int i = 0; i < 4; ++i)
#pragma unroll
        for (int j = 0; j < 4; ++j)
          acc[i][j] = fmaf(ar[i], br[j], acc[i][j]);
    }
    __syncthreads();
  }
#pragma unroll
  for (int i = 0; i < 4; ++i) {
    int row = m0 + (ty << 2) + i;
#pragma unroll
    for (int j = 0; j < 4; ++j) {
      int col = n0 + (tx << 2) + j;
      if (col < N) {
        float v = acc[i][j];
        if (bias) v += bias[col];
        int cc = remap68 ? col + ((col >> 6) << 2) : col;
        C[(size_t)row * ldc + cc] = v;
      }
    }
  }
}

// ---------- C[M,N] = A[M,K](lda) @ B[K,N](ldb); optional exp(A*ascale) on staging ----------
// split-K over gridDim.z: slice z writes partial C at C + z*partStride
__global__ __launch_bounds__(256) void k_gemm_nn(
    const float* __restrict__ A, int lda,
    const float* __restrict__ B, int ldb,
    float* __restrict__ C, int ldc,
    int M, int N, int K, int expA, float ascale, size_t partStride) {
  __shared__ float As[BK][TILE + 4];
  __shared__ float Bs[BK][TILE + 4];
  int tid = threadIdx.x;
  int m0 = blockIdx.x * TILE;
  int n0 = blockIdx.y * TILE;
  int kper = K / gridDim.z;
  int kbeg = blockIdx.z * kper;
  int kend = kbeg + kper;
  C += (size_t)blockIdx.z * partStride;
  int ty = tid >> 4, tx = tid & 15;
  int lr = tid >> 2;
  int lk = (tid & 3) << 2;
  int bkr = tid >> 4;
  int bn4 = (tid & 15) << 2;
  bool bfull = (n0 + TILE <= N);
  float acc[4][4] = {};
  for (int k0 = kbeg; k0 < kend; k0 += BK) {
    float4 va = *(const float4*)(A + (size_t)(m0 + lr) * lda + k0 + lk);
    if (expA) {
      va.x = __expf(va.x * ascale); va.y = __expf(va.y * ascale);
      va.z = __expf(va.z * ascale); va.w = __expf(va.w * ascale);
    }
    As[lk + 0][lr] = va.x; As[lk + 1][lr] = va.y;
    As[lk + 2][lr] = va.z; As[lk + 3][lr] = va.w;
    const float* bp = B + (size_t)(k0 + bkr) * ldb + n0 + bn4;
    if (bfull) {
      float4 vb = *(const float4*)bp;
      Bs[bkr][bn4 + 0] = vb.x; Bs[bkr][bn4 + 1] = vb.y;
      Bs[bkr][bn4 + 2] = vb.z; Bs[bkr][bn4 + 3] = vb.w;
    } else {
#pragma unroll
      for (int j = 0; j < 4; ++j)
        Bs[bkr][bn4 + j] = (n0 + bn4 + j < N) ? bp[j] : 0.f;
    }
    __syncthreads();
#pragma unroll
    for (int kk = 0; kk < BK; ++kk) {
      float4 a4 = *(const float4*)&As[kk][ty << 2];
      float4 b4 = *(const float4*)&Bs[kk][tx << 2];
      float ar[4] = {a4.x, a4.y, a4.z, a4.w};
      float br[4] = {b4.x, b4.y, b4.z, b4.w};
#pragma unroll
      for (int i = 0; i < 4; ++i)
#pragma unroll
        for (int j = 0; j < 4; ++j)
          acc[i][j] = fmaf(ar[i], br[j], acc[i][j]);
    }
    __syncthreads();
  }
#pragma unroll
  for (int i = 0; i < 4; ++i) {
    int row = m0 + (ty << 2) + i;
#pragma unroll
    for (int j = 0; j < 4; ++j) {
      int col = n0 + (tx << 2) + j;
      if (col < N) C[(size_t)row * ldc + col] = acc[i][j];
    }
  }
}

// ---------- sum split-K partials ----------
__global__ void k_sumk(const float* __restrict__ part, size_t pstride, int nsl,
                       float* __restrict__ out, int ld, int cols) {
  int r = blockIdx.y;
  int c = blockIdx.x * 256 + threadIdx.x;
  if (c >= cols) return;
  float s = 0.f;
  for (int z = 0; z < nsl; ++z) s += part[(size_t)z * pstride + (size_t)r * ld + c];
  out[(size_t)r * ld + c] = s;
}

// ---------- set ones / zero pad cols of V1x (ld 272, 4 heads) ----------
__global__ void k_fix1(float* __restrict__ v) {
  int idx = blockIdx.x * 256 + threadIdx.x;   // NN*16
  int r = idx >> 4, h = (idx >> 2) & 3, j = idx & 3;
  v[(size_t)r * 272 + h * 68 + 64 + j] = (j == 0) ? 1.f : 0.f;
}
// ---------- same for V2x (ld 68, 1 head) ----------
__global__ void k_fix2(float* __restrict__ v) {
  int idx = blockIdx.x * 256 + threadIdx.x;   // NN*4
  int r = idx >> 2, j = idx & 3;
  v[(size_t)r * 68 + 64 + j] = (j == 0) ? 1.f : 0.f;
}

// ---------- finalize: sum partials, ret = num/(den+1e-9), elu, strided store ----------
__global__ void k_fin(const float* __restrict__ part, size_t pstride, int nsl,
                      float* __restrict__ h, int ldh, int col0, int row0) {
  int idx = blockIdx.x * 256 + threadIdx.x;   // CH*64
  int r = idx >> 6, d = idx & 63;
  float nm = 0.f, dn = 0.f;
  for (int z = 0; z < nsl; ++z) {
    const float* p = part + (size_t)z * pstride + (size_t)r * 68;
    nm += p[d];
    dn += p[64];
  }
  float x = nm / (dn + 1e-9f);
  x = x > 0.f ? x : expm1f(x);
  h[(size_t)(row0 + r) * ldh + col0 + d] = x;
}

extern "C" void kernel_launch(void* const* d_in, const int* in_sizes, int n_in,
                              void* d_out, int out_size, void* d_ws, size_t ws_size,
                              hipStream_t stream) {
  (void)in_sizes; (void)n_in; (void)out_size; (void)ws_size;
  const float* feats    = (const float*)d_in[0];
  const float* counting = (const float*)d_in[1];
  const float* Wq1 = (const float*)d_in[2];
  const float* Wk1 = (const float*)d_in[3];
  const float* Wv1 = (const float*)d_in[4];
  const float* Wq2 = (const float*)d_in[5];
  const float* Wk2 = (const float*)d_in[6];
  const float* Wv2 = (const float*)d_in[7];
  const float* Wc  = (const float*)d_in[8];
  const float* bc  = (const float*)d_in[9];
  float* out = (float*)d_out;

  char* w = (char*)d_ws;
  float* hn   = (float*)(w + 0);          // 8388608   [4096,512]
  float* Q1   = (float*)(w + 8388608);    // 4194304   [4096,256]
  float* K1   = (float*)(w + 12582912);   // 4194304
  float* V1x  = (float*)(w + 16777216);   // 4456448   [4096,272] = 4x[64 V | 1 | pad3]
  float* CVX1 = (float*)(w + 21233664);   // 4456448   counting @ V1x
  float* h1   = (float*)(w + 25690112);   // 4194304   [4096,256]
  float* Q2   = (float*)(w + 29884416);   // 1048576   [4096,64]
  float* K2   = (float*)(w + 30932992);   // 1048576
  float* V2x  = (float*)(w + 31981568);   // 1114112   [4096,68]
  float* CVX2 = (float*)(w + 33095680);   // 1114112
  float* h2   = (float*)(w + 34209792);   // 1048576   [4096,64]
  float* numb = (float*)(w + 35258368);   // 2228224   8x[1024,68] partials
  float* E    = (float*)(w + 37486592);   // 16777216  [1024,4096] logits chunk / CVX partials
  // total 54263808 bytes (~51.8 MB)

  k_norm<<<NN / 4, 256, 0, stream>>>(feats, hn);

  // layer-1 projections
  k_gemm_bt<<<dim3(NN / 64, HD1 / 64), 256, 0, stream>>>(hn, IND, Wq1, IND, Q1, HD1, NN, HD1, IND, nullptr, 0);
  k_gemm_bt<<<dim3(NN / 64, HD1 / 64), 256, 0, stream>>>(hn, IND, Wk1, IND, K1, HD1, NN, HD1, IND, nullptr, 0);
  k_gemm_bt<<<dim3(NN / 64, HD1 / 64), 256, 0, stream>>>(hn, IND, Wv1, IND, V1x, 272, NN, HD1, IND, nullptr, 1);
  k_fix1<<<NN * 16 / 256, 256, 0, stream>>>(V1x);

  // CVX1 = counting @ [V1 | 1]  (split-K=2, partials in E)
  k_gemm_nn<<<dim3(NN / 64, 5, 2), 256, 0, stream>>>(counting, NN, V1x, 272, E, 272, NN, 272, NN, 0, 0.f, (size_t)NN * 272);
  k_sumk<<<dim3(2, NN), 256, 0, stream>>>(E, (size_t)NN * 272, 2, CVX1, 272, 272);

  // layer-1 attention, per head, per 1024-row chunk
  for (int h = 0; h < HEADS; ++h)
    for (int c = 0; c < NN / CH; ++c) {
      k_gemm_bt<<<dim3(CH / 64, NN / 64), 256, 0, stream>>>(
          Q1 + (size_t)c * CH * HD1 + h * HD, HD1, K1 + h * HD, HD1, E, NN, CH, NN, HD, nullptr, 0);
      k_gemm_nn<<<dim3(CH / 64, 2, 8), 256, 0, stream>>>(
          E, NN, CVX1 + h * 68, 272, numb, 68, CH, 65, NN, 1, 0.125f, (size_t)CH * 68);
      k_fin<<<CH * 64 / 256, 256, 0, stream>>>(numb, (size_t)CH * 68, 8, h1, HD1, h * HD, c * CH);
    }

  // layer-2 projections
  k_gemm_bt<<<dim3(NN / 64, 1), 256, 0, stream>>>(h1, HD1, Wq2, HD1, Q2, HD, NN, HD, HD1, nullptr, 0);
  k_gemm_bt<<<dim3(NN / 64, 1), 256, 0, stream>>>(h1, HD1, Wk2, HD1, K2, HD, NN, HD, HD1, nullptr, 0);
  k_gemm_bt<<<dim3(NN / 64, 1), 256, 0, stream>>>(h1, HD1, Wv2, HD1, V2x, 68, NN, HD, HD1, nullptr, 0);
  k_fix2<<<NN * 4 / 256, 256, 0, stream>>>(V2x);

  // CVX2 = counting @ [V2 | 1]  (split-K=4, partials in E)
  k_gemm_nn<<<dim3(NN / 64, 2, 4), 256, 0, stream>>>(counting, NN, V2x, 68, E, 68, NN, 65, NN, 0, 0.f, (size_t)NN * 68);
  k_sumk<<<dim3(1, NN), 256, 0, stream>>>(E, (size_t)NN * 68, 4, CVX2, 68, 65);

  // layer-2 attention
  for (int c = 0; c < NN / CH; ++c) {
    k_gemm_bt<<<dim3(CH / 64, NN / 64), 256, 0, stream>>>(
        Q2 + (size_t)c * CH * HD, HD, K2, HD, E, NN, CH, NN, HD, nullptr, 0);
    k_gemm_nn<<<dim3(CH / 64, 2, 8), 256, 0, stream>>>(
        E, NN, CVX2, 68, numb, 68, CH, 65, NN, 1, 0.125f, (size_t)CH * 68);
    k_fin<<<CH * 64 / 256, 256, 0, stream>>>(numb, (size_t)CH * 68, 8, h2, HD, 0, c * CH);
  }

  // classifier
  k_gemm_bt<<<dim3(NN / 64, 1), 256, 0, stream>>>(h2, HD, Wc, HD, out, NC, NN, NC, HD, bc, 0);
}

// Round 2
// 482.962 us; speedup vs baseline: 3.3078x; 3.3078x over previous
//
#include <hip/hip_runtime.h>
#include <math.h>

#define NN4   4096
#define CHK   2048

typedef __attribute__((ext_vector_type(8))) short short8;
typedef __attribute__((ext_vector_type(8))) unsigned short ushort8;
typedef __attribute__((ext_vector_type(4))) unsigned short ushort4v;
typedef __attribute__((ext_vector_type(4))) float f32x4;

__device__ __forceinline__ unsigned short f2b(float f) {
  unsigned int u = __float_as_uint(f);
  u += 0x7FFFu + ((u >> 16) & 1u);
  return (unsigned short)(u >> 16);
}
__device__ __forceinline__ float b2f(unsigned short s) {
  return __uint_as_float(((unsigned int)s) << 16);
}

// ---------------- row normalize (mean/std over 512, ddof=1) -> bf16 ----------------
__global__ __launch_bounds__(256) void k_norm(const float* __restrict__ x,
                                              unsigned short* __restrict__ y) {
  int row  = blockIdx.x * 4 + (threadIdx.x >> 6);
  int lane = threadIdx.x & 63;
  const float4* src = (const float4*)(x + (size_t)row * 512);
  float4 a = src[lane];
  float4 b = src[lane + 64];
  float s = a.x + a.y + a.z + a.w + b.x + b.y + b.z + b.w;
#pragma unroll
  for (int off = 32; off; off >>= 1) s += __shfl_xor(s, off);
  float mean = s * (1.0f / 512.0f);
  float ssq = 0.f, d;
  d = a.x - mean; ssq += d * d;  d = a.y - mean; ssq += d * d;
  d = a.z - mean; ssq += d * d;  d = a.w - mean; ssq += d * d;
  d = b.x - mean; ssq += d * d;  d = b.y - mean; ssq += d * d;
  d = b.z - mean; ssq += d * d;  d = b.w - mean; ssq += d * d;
#pragma unroll
  for (int off = 32; off; off >>= 1) ssq += __shfl_xor(ssq, off);
  float inv = 1.0f / (sqrtf(ssq * (1.0f / 511.0f)) + 1e-9f);
  unsigned short* dst = y + (size_t)row * 512;
  ushort4v va = (ushort4v){f2b((a.x - mean) * inv), f2b((a.y - mean) * inv),
                           f2b((a.z - mean) * inv), f2b((a.w - mean) * inv)};
  ushort4v vb = (ushort4v){f2b((b.x - mean) * inv), f2b((b.y - mean) * inv),
                           f2b((b.z - mean) * inv), f2b((b.w - mean) * inv)};
  *(ushort4v*)(dst + lane * 4)       = va;
  *(ushort4v*)(dst + 256 + lane * 4) = vb;
}

// ------------------- MFMA GEMM: C[M,N] = A[M,K] @ B[N,K]^T -------------------
// AF32/BF32: operand stored as f32 (convert to bf16 while staging) else bf16.
// EPI: 0 = f32 store with split-K (C += blockIdx.z*partStride)
//      1 = bf16 store
//      2 = bf16 store with row remap r -> r + 4*(r>>6)   (build V^T w/ ones slots)
//      3 = bf16 store of exp(acc*ascale)
#define LDSP 40
template<int AF32, int BF32, int EPI>
__global__ __launch_bounds__(256) void k_mfma(
    const void* __restrict__ Ap, int lda,
    const void* __restrict__ Bp, int ldb,
    void* __restrict__ Cp, int ldc,
    int M, int N, int K, float ascale, unsigned long long partStride) {
  __shared__ unsigned short As[128 * LDSP];
  __shared__ unsigned short Bs[128 * LDSP];
  const int tid = threadIdx.x;
  const int m0 = blockIdx.x * 128, n0 = blockIdx.y * 128;
  const int kper = K / gridDim.z;
  const int kbeg = blockIdx.z * kper, kend = kbeg + kper;
  const int lane = tid & 63, wid = tid >> 6;
  const int wr = (wid >> 1) << 6, wc = (wid & 1) << 6;
  const int srow = tid >> 1, sk = (tid & 1) << 4;   // this thread stages 16 elems
  f32x4 acc[4][4];
#pragma unroll
  for (int i = 0; i < 4; ++i)
#pragma unroll
    for (int j = 0; j < 4; ++j) acc[i][j] = (f32x4){0.f, 0.f, 0.f, 0.f};

  for (int k0 = kbeg; k0 < kend; k0 += 32) {
    ushort8 va0, va1, vb0, vb1;
    {
      int gr = m0 + srow;
      if (gr < M) {
        if constexpr (AF32) {
          const float* s = (const float*)Ap + (size_t)gr * lda + k0 + sk;
          float4 f0 = *(const float4*)(s);
          float4 f1 = *(const float4*)(s + 4);
          float4 f2 = *(const float4*)(s + 8);
          float4 f3 = *(const float4*)(s + 12);
          va0 = (ushort8){f2b(f0.x), f2b(f0.y), f2b(f0.z), f2b(f0.w),
                          f2b(f1.x), f2b(f1.y), f2b(f1.z), f2b(f1.w)};
          va1 = (ushort8){f2b(f2.x), f2b(f2.y), f2b(f2.z), f2b(f2.w),
                          f2b(f3.x), f2b(f3.y), f2b(f3.z), f2b(f3.w)};
        } else {
          const unsigned short* s = (const unsigned short*)Ap + (size_t)gr * lda + k0 + sk;
          va0 = *(const ushort8*)(s);
          va1 = *(const ushort8*)(s + 8);
        }
      } else { va0 = (ushort8)0; va1 = (ushort8)0; }
    }
    {
      int gr = n0 + srow;
      if (gr < N) {
        if constexpr (BF32) {
          const float* s = (const float*)Bp + (size_t)gr * ldb + k0 + sk;
          float4 f0 = *(const float4*)(s);
          float4 f1 = *(const float4*)(s + 4);
          float4 f2 = *(const float4*)(s + 8);
          float4 f3 = *(const float4*)(s + 12);
          vb0 = (ushort8){f2b(f0.x), f2b(f0.y), f2b(f0.z), f2b(f0.w),
                          f2b(f1.x), f2b(f1.y), f2b(f1.z), f2b(f1.w)};
          vb1 = (ushort8){f2b(f2.x), f2b(f2.y), f2b(f2.z), f2b(f2.w),
                          f2b(f3.x), f2b(f3.y), f2b(f3.z), f2b(f3.w)};
        } else {
          const unsigned short* s = (const unsigned short*)Bp + (size_t)gr * ldb + k0 + sk;
          vb0 = *(const ushort8*)(s);
          vb1 = *(const ushort8*)(s + 8);
        }
      } else { vb0 = (ushort8)0; vb1 = (ushort8)0; }
    }
    __syncthreads();
    *(ushort8*)&As[srow * LDSP + sk]     = va0;
    *(ushort8*)&As[srow * LDSP + sk + 8] = va1;
    *(ushort8*)&Bs[srow * LDSP + sk]     = vb0;
    *(ushort8*)&Bs[srow * LDSP + sk + 8] = vb1;
    __syncthreads();
    short8 af[4], bf[4];
#pragma unroll
    for (int i = 0; i < 4; ++i)
      af[i] = *(const short8*)&As[(wr + (i << 4) + (lane & 15)) * LDSP + ((lane >> 4) << 3)];
#pragma unroll
    for (int j = 0; j < 4; ++j)
      bf[j] = *(const short8*)&Bs[(wc + (j << 4) + (lane & 15)) * LDSP + ((lane >> 4) << 3)];
#pragma unroll
    for (int i = 0; i < 4; ++i)
#pragma unroll
      for (int j = 0; j < 4; ++j)
        acc[i][j] = __builtin_amdgcn_mfma_f32_16x16x32_bf16(af[i], bf[j], acc[i][j], 0, 0, 0);
  }

  // epilogue: C/D layout col=lane&15, row=(lane>>4)*4+reg
#pragma unroll
  for (int i = 0; i < 4; ++i) {
#pragma unroll
    for (int j = 0; j < 4; ++j) {
#pragma unroll
      for (int reg = 0; reg < 4; ++reg) {
        int r = m0 + wr + (i << 4) + ((lane >> 4) << 2) + reg;
        int c = n0 + wc + (j << 4) + (lane & 15);
        if (r < M && c < N) {
          float v = acc[i][j][reg];
          if constexpr (EPI == 0) {
            float* C = (float*)Cp + (size_t)blockIdx.z * partStride;
            C[(size_t)r * ldc + c] = v;
          } else if constexpr (EPI == 1) {
            ((unsigned short*)Cp)[(size_t)r * ldc + c] = f2b(v);
          } else if constexpr (EPI == 2) {
            int r2 = r + ((r >> 6) << 2);
            ((unsigned short*)Cp)[(size_t)r2 * ldc + c] = f2b(v);
          } else {
            ((unsigned short*)Cp)[(size_t)r * ldc + c] = f2b(__expf(v * ascale));
          }
        }
      }
    }
  }
}

// ---------- set ones/zero pad rows of V^T buffers: row h*68+64+j = (j==0) ----------
__global__ void k_fix(unsigned short* __restrict__ v) {
  int idx = blockIdx.x * 256 + threadIdx.x;
  int h = idx >> 14, j = (idx >> 12) & 3, n = idx & 4095;
  v[(size_t)(h * 68 + 64 + j) * NN4 + n] = (j == 0) ? 0x3F80 : 0;
}

// ---------- transpose-reduce split-K partials -> bf16 [D][4096] ----------
__global__ void k_tred(const float* __restrict__ part, unsigned long long pstride,
                       int ldin, int nsl, unsigned short* __restrict__ outb) {
  int idx = blockIdx.x * 256 + threadIdx.x;
  int d = idx >> 12, n = idx & 4095;
  float s = 0.f;
  for (int z = 0; z < nsl; ++z) s += part[(size_t)z * pstride + (size_t)n * ldin + d];
  outb[(size_t)d * NN4 + n] = f2b(s);
}

// ---------- finalize: sum partials, x = num/(den+1e-9), elu, bf16 store ----------
__global__ void k_fin(const float* __restrict__ part, unsigned long long pstride, int nsl,
                      unsigned short* __restrict__ h, int ldh, int col0, int row0) {
  int idx = blockIdx.x * 256 + threadIdx.x;    // CHK*64
  int r = idx >> 6, d = idx & 63;
  float nm = 0.f, dn = 0.f;
  for (int z = 0; z < nsl; ++z) {
    const float* p = part + (size_t)z * pstride + (size_t)r * 80;
    nm += p[d];
    dn += p[64];
  }
  float x = nm / (dn + 1e-9f);
  x = x > 0.f ? x : expm1f(x);
  h[(size_t)(row0 + r) * ldh + col0 + d] = f2b(x);
}

// ---------- classifier: out[4096,10] = h2 @ Wc^T + bc (f32) ----------
__global__ void k_cls(const unsigned short* __restrict__ h2, const float* __restrict__ Wc,
                      const float* __restrict__ bc, float* __restrict__ out) {
  int idx = blockIdx.x * 256 + threadIdx.x;
  int r = idx >> 4, cl = idx & 15;
  if (cl >= 10) return;
  float s = 0.f;
  for (int k = 0; k < 64; ++k) s += b2f(h2[(size_t)r * 64 + k]) * Wc[cl * 64 + k];
  out[(size_t)r * 10 + cl] = s + bc[cl];
}

extern "C" void kernel_launch(void* const* d_in, const int* in_sizes, int n_in,
                              void* d_out, int out_size, void* d_ws, size_t ws_size,
                              hipStream_t stream) {
  (void)in_sizes; (void)n_in; (void)out_size; (void)ws_size;
  const float* feats    = (const float*)d_in[0];
  const float* counting = (const float*)d_in[1];
  const float* Wq1 = (const float*)d_in[2];
  const float* Wk1 = (const float*)d_in[3];
  const float* Wv1 = (const float*)d_in[4];
  const float* Wq2 = (const float*)d_in[5];
  const float* Wk2 = (const float*)d_in[6];
  const float* Wv2 = (const float*)d_in[7];
  const float* Wc  = (const float*)d_in[8];
  const float* bc  = (const float*)d_in[9];
  float* out = (float*)d_out;

  char* w = (char*)d_ws;
  size_t off = 0;
  auto alloc = [&](size_t bytes) { void* p = w + off; off += (bytes + 255) & ~(size_t)255; return p; };
  unsigned short* hnb    = (unsigned short*)alloc((size_t)4096 * 512 * 2);
  unsigned short* Q1b    = (unsigned short*)alloc((size_t)4096 * 256 * 2);
  unsigned short* K1b    = (unsigned short*)alloc((size_t)4096 * 256 * 2);
  unsigned short* V1xT   = (unsigned short*)alloc((size_t)272 * 4096 * 2);
  unsigned short* CVX1Tb = (unsigned short*)alloc((size_t)272 * 4096 * 2);
  unsigned short* h1b    = (unsigned short*)alloc((size_t)4096 * 256 * 2);
  unsigned short* Q2b    = (unsigned short*)alloc((size_t)4096 * 64 * 2);
  unsigned short* K2b    = (unsigned short*)alloc((size_t)4096 * 64 * 2);
  unsigned short* V2xT   = (unsigned short*)alloc((size_t)68 * 4096 * 2);
  unsigned short* CVX2Tb = (unsigned short*)alloc((size_t)68 * 4096 * 2);
  unsigned short* h2b    = (unsigned short*)alloc((size_t)4096 * 64 * 2);
  unsigned short* Eb     = (unsigned short*)alloc((size_t)CHK * 4096 * 2);
  float*          parts  = (float*)alloc((size_t)4 * 4096 * 272 * 4);  // also reused for num partials

  k_norm<<<1024, 256, 0, stream>>>(feats, hnb);

  // layer-1 projections (bf16 out); V produced transposed w/ per-head row remap
  k_mfma<0,1,1><<<dim3(32, 2), 256, 0, stream>>>(hnb, 512, Wq1, 512, Q1b, 256, 4096, 256, 512, 0.f, 0);
  k_mfma<0,1,1><<<dim3(32, 2), 256, 0, stream>>>(hnb, 512, Wk1, 512, K1b, 256, 4096, 256, 512, 0.f, 0);
  k_mfma<1,0,2><<<dim3(2, 32), 256, 0, stream>>>(Wv1, 512, hnb, 512, V1xT, 4096, 256, 4096, 512, 0.f, 0);
  k_fix<<<256, 256, 0, stream>>>(V1xT);   // 4 heads

  // CVX1 = counting @ [V1|1]  -> split-K f32 partials -> transpose-reduce -> bf16 [272][4096]
  k_mfma<1,0,0><<<dim3(32, 3, 4), 256, 0, stream>>>(counting, 4096, V1xT, 4096, parts, 272,
                                                    4096, 272, 4096, 0.f, (unsigned long long)4096 * 272);
  k_tred<<<272 * 4096 / 256, 256, 0, stream>>>(parts, (unsigned long long)4096 * 272, 272, 4, CVX1Tb);

  // layer-1 attention: per head, per 2048-row chunk
  for (int h = 0; h < 4; ++h)
    for (int c = 0; c < 2; ++c) {
      k_mfma<0,0,3><<<dim3(16, 32), 256, 0, stream>>>(
          Q1b + (size_t)c * CHK * 256 + h * 64, 256, K1b + h * 64, 256, Eb, 4096,
          CHK, 4096, 64, 0.125f, 0);
      k_mfma<0,0,0><<<dim3(16, 1, 16), 256, 0, stream>>>(
          Eb, 4096, CVX1Tb + (size_t)h * 68 * 4096, 4096, parts, 80,
          CHK, 68, 4096, 0.f, (unsigned long long)CHK * 80);
      k_fin<<<CHK * 64 / 256, 256, 0, stream>>>(parts, (unsigned long long)CHK * 80, 16,
                                                h1b, 256, h * 64, c * CHK);
    }

  // layer-2 projections
  k_mfma<0,1,1><<<dim3(32, 1), 256, 0, stream>>>(h1b, 256, Wq2, 256, Q2b, 64, 4096, 64, 256, 0.f, 0);
  k_mfma<0,1,1><<<dim3(32, 1), 256, 0, stream>>>(h1b, 256, Wk2, 256, K2b, 64, 4096, 64, 256, 0.f, 0);
  k_mfma<1,0,2><<<dim3(1, 32), 256, 0, stream>>>(Wv2, 256, h1b, 256, V2xT, 4096, 64, 4096, 256, 0.f, 0);
  k_fix<<<64, 256, 0, stream>>>(V2xT);    // 1 head

  // CVX2
  k_mfma<1,0,0><<<dim3(32, 1, 4), 256, 0, stream>>>(counting, 4096, V2xT, 4096, parts, 80,
                                                    4096, 68, 4096, 0.f, (unsigned long long)4096 * 80);
  k_tred<<<68 * 4096 / 256, 256, 0, stream>>>(parts, (unsigned long long)4096 * 80, 80, 4, CVX2Tb);

  // layer-2 attention
  for (int c = 0; c < 2; ++c) {
    k_mfma<0,0,3><<<dim3(16, 32), 256, 0, stream>>>(
        Q2b + (size_t)c * CHK * 64, 64, K2b, 64, Eb, 4096, CHK, 4096, 64, 0.125f, 0);
    k_mfma<0,0,0><<<dim3(16, 1, 16), 256, 0, stream>>>(
        Eb, 4096, CVX2Tb, 4096, parts, 80, CHK, 68, 4096, 0.f, (unsigned long long)CHK * 80);
    k_fin<<<CHK * 64 / 256, 256, 0, stream>>>(parts, (unsigned long long)CHK * 80, 16,
                                              h2b, 64, 0, c * CHK);
  }

  k_cls<<<256, 256, 0, stream>>>(h2b, Wc, bc, out);
}

// Round 3
// 275.499 us; speedup vs baseline: 5.7988x; 1.7530x over previous
//
#include <hip/hip_runtime.h>
#include <math.h>

#define NN4   4096

typedef __attribute__((ext_vector_type(8))) short short8;
typedef __attribute__((ext_vector_type(8))) unsigned short ushort8;
typedef __attribute__((ext_vector_type(4))) unsigned short ushort4v;
typedef __attribute__((ext_vector_type(4))) float f32x4;

__device__ __forceinline__ unsigned short f2b(float f) {
  unsigned int u = __float_as_uint(f);
  u += 0x7FFFu + ((u >> 16) & 1u);
  return (unsigned short)(u >> 16);
}
__device__ __forceinline__ float b2f(unsigned short s) {
  return __uint_as_float(((unsigned int)s) << 16);
}

// ---------------- row normalize (mean/std over 512, ddof=1) -> bf16 ----------------
__global__ __launch_bounds__(256) void k_norm(const float* __restrict__ x,
                                              unsigned short* __restrict__ y) {
  int row  = blockIdx.x * 4 + (threadIdx.x >> 6);
  int lane = threadIdx.x & 63;
  const float4* src = (const float4*)(x + (size_t)row * 512);
  float4 a = src[lane];
  float4 b = src[lane + 64];
  float s = a.x + a.y + a.z + a.w + b.x + b.y + b.z + b.w;
#pragma unroll
  for (int off = 32; off; off >>= 1) s += __shfl_xor(s, off);
  float mean = s * (1.0f / 512.0f);
  float ssq = 0.f, d;
  d = a.x - mean; ssq += d * d;  d = a.y - mean; ssq += d * d;
  d = a.z - mean; ssq += d * d;  d = a.w - mean; ssq += d * d;
  d = b.x - mean; ssq += d * d;  d = b.y - mean; ssq += d * d;
  d = b.z - mean; ssq += d * d;  d = b.w - mean; ssq += d * d;
#pragma unroll
  for (int off = 32; off; off >>= 1) ssq += __shfl_xor(ssq, off);
  float inv = 1.0f / (sqrtf(ssq * (1.0f / 511.0f)) + 1e-9f);
  unsigned short* dst = y + (size_t)row * 512;
  ushort4v va = (ushort4v){f2b((a.x - mean) * inv), f2b((a.y - mean) * inv),
                           f2b((a.z - mean) * inv), f2b((a.w - mean) * inv)};
  ushort4v vb = (ushort4v){f2b((b.x - mean) * inv), f2b((b.y - mean) * inv),
                           f2b((b.z - mean) * inv), f2b((b.w - mean) * inv)};
  *(ushort4v*)(dst + lane * 4)       = va;
  *(ushort4v*)(dst + 256 + lane * 4) = vb;
}

// ------------------- MFMA GEMM: C[M,N] = A[M,K] @ B[N,K]^T -------------------
// EPI: 0 = f32 split-K partial store, 1 = bf16, 2 = bf16 row-remapped (V^T build)
#define LDSP 40
template<int AF32, int BF32, int EPI>
__global__ __launch_bounds__(256) void k_mfma(
    const void* __restrict__ Ap, int lda,
    const void* __restrict__ Bp, int ldb,
    void* __restrict__ Cp, int ldc,
    int M, int N, int K, unsigned long long partStride) {
  __shared__ unsigned short As[128 * LDSP];
  __shared__ unsigned short Bs[128 * LDSP];
  const int tid = threadIdx.x;
  const int m0 = blockIdx.x * 128, n0 = blockIdx.y * 128;
  const int kper = K / gridDim.z;
  const int kbeg = blockIdx.z * kper, kend = kbeg + kper;
  const int lane = tid & 63, wid = tid >> 6;
  const int wr = (wid >> 1) << 6, wc = (wid & 1) << 6;
  const int srow = tid >> 1, sk = (tid & 1) << 4;
  f32x4 acc[4][4];
#pragma unroll
  for (int i = 0; i < 4; ++i)
#pragma unroll
    for (int j = 0; j < 4; ++j) acc[i][j] = (f32x4){0.f, 0.f, 0.f, 0.f};

  for (int k0 = kbeg; k0 < kend; k0 += 32) {
    ushort8 va0, va1, vb0, vb1;
    {
      int gr = m0 + srow;
      if (gr < M) {
        if constexpr (AF32) {
          const float* s = (const float*)Ap + (size_t)gr * lda + k0 + sk;
          float4 f0 = *(const float4*)(s);
          float4 f1 = *(const float4*)(s + 4);
          float4 f2 = *(const float4*)(s + 8);
          float4 f3 = *(const float4*)(s + 12);
          va0 = (ushort8){f2b(f0.x), f2b(f0.y), f2b(f0.z), f2b(f0.w),
                          f2b(f1.x), f2b(f1.y), f2b(f1.z), f2b(f1.w)};
          va1 = (ushort8){f2b(f2.x), f2b(f2.y), f2b(f2.z), f2b(f2.w),
                          f2b(f3.x), f2b(f3.y), f2b(f3.z), f2b(f3.w)};
        } else {
          const unsigned short* s = (const unsigned short*)Ap + (size_t)gr * lda + k0 + sk;
          va0 = *(const ushort8*)(s);
          va1 = *(const ushort8*)(s + 8);
        }
      } else { va0 = (ushort8)0; va1 = (ushort8)0; }
    }
    {
      int gr = n0 + srow;
      if (gr < N) {
        if constexpr (BF32) {
          const float* s = (const float*)Bp + (size_t)gr * ldb + k0 + sk;
          float4 f0 = *(const float4*)(s);
          float4 f1 = *(const float4*)(s + 4);
          float4 f2 = *(const float4*)(s + 8);
          float4 f3 = *(const float4*)(s + 12);
          vb0 = (ushort8){f2b(f0.x), f2b(f0.y), f2b(f0.z), f2b(f0.w),
                          f2b(f1.x), f2b(f1.y), f2b(f1.z), f2b(f1.w)};
          vb1 = (ushort8){f2b(f2.x), f2b(f2.y), f2b(f2.z), f2b(f2.w),
                          f2b(f3.x), f2b(f3.y), f2b(f3.z), f2b(f3.w)};
        } else {
          const unsigned short* s = (const unsigned short*)Bp + (size_t)gr * ldb + k0 + sk;
          vb0 = *(const ushort8*)(s);
          vb1 = *(const ushort8*)(s + 8);
        }
      } else { vb0 = (ushort8)0; vb1 = (ushort8)0; }
    }
    __syncthreads();
    *(ushort8*)&As[srow * LDSP + sk]     = va0;
    *(ushort8*)&As[srow * LDSP + sk + 8] = va1;
    *(ushort8*)&Bs[srow * LDSP + sk]     = vb0;
    *(ushort8*)&Bs[srow * LDSP + sk + 8] = vb1;
    __syncthreads();
    short8 af[4], bf[4];
#pragma unroll
    for (int i = 0; i < 4; ++i)
      af[i] = *(const short8*)&As[(wr + (i << 4) + (lane & 15)) * LDSP + ((lane >> 4) << 3)];
#pragma unroll
    for (int j = 0; j < 4; ++j)
      bf[j] = *(const short8*)&Bs[(wc + (j << 4) + (lane & 15)) * LDSP + ((lane >> 4) << 3)];
#pragma unroll
    for (int i = 0; i < 4; ++i)
#pragma unroll
      for (int j = 0; j < 4; ++j)
        acc[i][j] = __builtin_amdgcn_mfma_f32_16x16x32_bf16(af[i], bf[j], acc[i][j], 0, 0, 0);
  }

#pragma unroll
  for (int i = 0; i < 4; ++i) {
#pragma unroll
    for (int j = 0; j < 4; ++j) {
#pragma unroll
      for (int reg = 0; reg < 4; ++reg) {
        int r = m0 + wr + (i << 4) + ((lane >> 4) << 2) + reg;
        int c = n0 + wc + (j << 4) + (lane & 15);
        if (r < M && c < N) {
          float v = acc[i][j][reg];
          if constexpr (EPI == 0) {
            float* C = (float*)Cp + (size_t)blockIdx.z * partStride;
            C[(size_t)r * ldc + c] = v;
          } else if constexpr (EPI == 1) {
            ((unsigned short*)Cp)[(size_t)r * ldc + c] = f2b(v);
          } else {
            int r2 = r + ((r >> 6) << 2);
            ((unsigned short*)Cp)[(size_t)r2 * ldc + c] = f2b(v);
          }
        }
      }
    }
  }
}

// ---------------- fused GKAT attention: num = exp(Q K^T / 8) @ CVX^T ----------------
// grid: (qblocks=32, heads, nsl). Each block: 128 Q rows, m-slice of 4096/nsl.
// Writes f32 partials [128][80] per (h,qb,sl); col 64 of CVX^T is the ones-row -> denom.
__global__ __launch_bounds__(256, 2) void k_attn(
    const unsigned short* __restrict__ Qg, const unsigned short* __restrict__ Kg,
    int ldqk, const unsigned short* __restrict__ CVg,
    float* __restrict__ parts) {
  __shared__ unsigned short Ks[128 * 72];
  __shared__ unsigned short Cs[80 * 136];
  __shared__ unsigned short Es[128 * 136];
  const int tid = threadIdx.x, lane = tid & 63, wid = tid >> 6;
  const int hi = lane >> 4, lo = lane & 15;
  const int qb = blockIdx.x, h = blockIdx.y, sl = blockIdx.z;
  const int n0 = qb * 128;
  const int MS = 4096 / gridDim.z;
  const int m0beg = sl * MS;
  const int wr = (wid >> 1) << 6, wc = (wid & 1) << 6;

  // persistent Q fragments (B operand of S^T): q-rows wc+16j+lo, k = t*32+hi*8
  short8 qf[4][2];
  const unsigned short* Qh = Qg + (size_t)h * 64;
#pragma unroll
  for (int j = 0; j < 4; ++j)
#pragma unroll
    for (int t = 0; t < 2; ++t)
      qf[j][t] = *(const short8*)(Qh + (size_t)(n0 + wc + 16 * j + lo) * ldqk + t * 32 + hi * 8);

  const unsigned short* CVh = CVg + (size_t)h * 68 * NN4;
  const unsigned short* Kh  = Kg + (size_t)h * 64;

  f32x4 accn[2][5];
#pragma unroll
  for (int i = 0; i < 2; ++i)
#pragma unroll
    for (int j = 0; j < 5; ++j) accn[i][j] = (f32x4){0.f, 0.f, 0.f, 0.f};

  for (int mt = 0; mt < MS; mt += 128) {
    const int m0 = m0beg + mt;
    __syncthreads();
    // stage K tile: 128 rows x 64 cols
    {
      const int row = tid >> 1, half = (tid & 1) << 5;
      const unsigned short* src = Kh + (size_t)(m0 + row) * ldqk + half;
      ushort8 v0 = *(const ushort8*)(src);
      ushort8 v1 = *(const ushort8*)(src + 8);
      ushort8 v2 = *(const ushort8*)(src + 16);
      ushort8 v3 = *(const ushort8*)(src + 24);
      unsigned short* dp = &Ks[row * 72 + half];
      *(ushort8*)(dp) = v0; *(ushort8*)(dp + 8) = v1;
      *(ushort8*)(dp + 16) = v2; *(ushort8*)(dp + 24) = v3;
    }
    // stage CVX^T tile: 80 rows (d; >=68 zero) x 128 cols (m)
#pragma unroll
    for (int k = 0; k < 5; ++k) {
      int c = tid + k * 256;          // 1280 chunks of 8
      int row = c >> 4, col = (c & 15) << 3;
      ushort8 v = (ushort8)0;
      if (row < 68) v = *(const ushort8*)(CVh + (size_t)row * NN4 + m0 + col);
      *(ushort8*)&Cs[row * 136 + col] = v;
    }
    __syncthreads();
    // S^T = K_tile · Q^T  (C[m][n])
    f32x4 s[4][4];
#pragma unroll
    for (int i = 0; i < 4; ++i)
#pragma unroll
      for (int j = 0; j < 4; ++j) s[i][j] = (f32x4){0.f, 0.f, 0.f, 0.f};
    short8 kf[4][2];
#pragma unroll
    for (int i = 0; i < 4; ++i)
#pragma unroll
      for (int t = 0; t < 2; ++t)
        kf[i][t] = *(const short8*)&Ks[(wr + 16 * i + lo) * 72 + t * 32 + hi * 8];
#pragma unroll
    for (int t = 0; t < 2; ++t)
#pragma unroll
      for (int i = 0; i < 4; ++i)
#pragma unroll
        for (int j = 0; j < 4; ++j)
          s[i][j] = __builtin_amdgcn_mfma_f32_16x16x32_bf16(kf[i][t], qf[j][t], s[i][j], 0, 0, 0);
    // E[n][m] = exp(S/8) -> bf16 LDS
#pragma unroll
    for (int i = 0; i < 4; ++i)
#pragma unroll
      for (int j = 0; j < 4; ++j) {
        unsigned int u0 = (unsigned int)f2b(__expf(s[i][j][0] * 0.125f)) |
                          ((unsigned int)f2b(__expf(s[i][j][1] * 0.125f)) << 16);
        unsigned int u1 = (unsigned int)f2b(__expf(s[i][j][2] * 0.125f)) |
                          ((unsigned int)f2b(__expf(s[i][j][3] * 0.125f)) << 16);
        unsigned long long pk = (unsigned long long)u0 | ((unsigned long long)u1 << 32);
        *(unsigned long long*)&Es[(size_t)(wc + 16 * j + lo) * 136 + wr + 16 * i + 4 * hi] = pk;
      }
    __syncthreads();
    // num += E (128 x 128) @ CVX^T tile^T  -> wave owns rows 32*wid..+31, cols 0..79
#pragma unroll
    for (int t2 = 0; t2 < 4; ++t2) {
      short8 ea0 = *(const short8*)&Es[(32 * wid + lo) * 136 + t2 * 32 + hi * 8];
      short8 ea1 = *(const short8*)&Es[(32 * wid + 16 + lo) * 136 + t2 * 32 + hi * 8];
      short8 cb[5];
#pragma unroll
      for (int j2 = 0; j2 < 5; ++j2)
        cb[j2] = *(const short8*)&Cs[(16 * j2 + lo) * 136 + t2 * 32 + hi * 8];
#pragma unroll
      for (int j2 = 0; j2 < 5; ++j2) {
        accn[0][j2] = __builtin_amdgcn_mfma_f32_16x16x32_bf16(ea0, cb[j2], accn[0][j2], 0, 0, 0);
        accn[1][j2] = __builtin_amdgcn_mfma_f32_16x16x32_bf16(ea1, cb[j2], accn[1][j2], 0, 0, 0);
      }
    }
  }
  // write partials [128][80] f32
  float* P = parts + (((size_t)h * gridDim.x + qb) * gridDim.z + sl) * (128 * 80);
#pragma unroll
  for (int i2 = 0; i2 < 2; ++i2)
#pragma unroll
    for (int j2 = 0; j2 < 5; ++j2)
#pragma unroll
      for (int reg = 0; reg < 4; ++reg) {
        int r = 32 * wid + 16 * i2 + 4 * hi + reg;
        int c = 16 * j2 + lo;
        P[(size_t)r * 80 + c] = accn[i2][j2][reg];
      }
}

// ---------- merge slices: x = num/(den+1e-9), elu, bf16 store ----------
__global__ void k_fin2(const float* __restrict__ parts, int nsl,
                       unsigned short* __restrict__ hb, int ldh) {
  int idx = blockIdx.x * 256 + threadIdx.x;
  int d = idx & 63, r = (idx >> 6) & 4095, h = idx >> 18;
  size_t b0 = ((size_t)(h * 32 + (r >> 7)) * nsl) * 10240 + (size_t)(r & 127) * 80;
  float nm = 0.f, dn = 0.f;
  for (int sl = 0; sl < nsl; ++sl) {
    const float* p = parts + b0 + (size_t)sl * 10240;
    nm += p[d]; dn += p[64];
  }
  float x = nm / (dn + 1e-9f);
  x = x > 0.f ? x : expm1f(x);
  hb[(size_t)r * ldh + h * 64 + d] = f2b(x);
}

// ---------- set ones/zero pad rows of V^T buffers: row h*68+64+j = (j==0) ----------
__global__ void k_fix(unsigned short* __restrict__ v) {
  int idx = blockIdx.x * 256 + threadIdx.x;
  int h = idx >> 14, j = (idx >> 12) & 3, n = idx & 4095;
  v[(size_t)(h * 68 + 64 + j) * NN4 + n] = (j == 0) ? 0x3F80 : 0;
}

// ---------- transpose-reduce split-K partials -> bf16 [D][4096] ----------
__global__ void k_tred(const float* __restrict__ part, unsigned long long pstride,
                       int ldin, int nsl, unsigned short* __restrict__ outb) {
  int idx = blockIdx.x * 256 + threadIdx.x;
  int d = idx >> 12, n = idx & 4095;
  float s = 0.f;
  for (int z = 0; z < nsl; ++z) s += part[(size_t)z * pstride + (size_t)n * ldin + d];
  outb[(size_t)d * NN4 + n] = f2b(s);
}

// ---------- classifier ----------
__global__ void k_cls(const unsigned short* __restrict__ h2, const float* __restrict__ Wc,
                      const float* __restrict__ bc, float* __restrict__ out) {
  int idx = blockIdx.x * 256 + threadIdx.x;
  int r = idx >> 4, cl = idx & 15;
  if (cl >= 10) return;
  float s = 0.f;
  for (int k = 0; k < 64; ++k) s += b2f(h2[(size_t)r * 64 + k]) * Wc[cl * 64 + k];
  out[(size_t)r * 10 + cl] = s + bc[cl];
}

extern "C" void kernel_launch(void* const* d_in, const int* in_sizes, int n_in,
                              void* d_out, int out_size, void* d_ws, size_t ws_size,
                              hipStream_t stream) {
  (void)in_sizes; (void)n_in; (void)out_size; (void)ws_size;
  const float* feats    = (const float*)d_in[0];
  const float* counting = (const float*)d_in[1];
  const float* Wq1 = (const float*)d_in[2];
  const float* Wk1 = (const float*)d_in[3];
  const float* Wv1 = (const float*)d_in[4];
  const float* Wq2 = (const float*)d_in[5];
  const float* Wk2 = (const float*)d_in[6];
  const float* Wv2 = (const float*)d_in[7];
  const float* Wc  = (const float*)d_in[8];
  const float* bc  = (const float*)d_in[9];
  float* out = (float*)d_out;

  char* w = (char*)d_ws;
  size_t off = 0;
  auto alloc = [&](size_t bytes) { void* p = w + off; off += (bytes + 255) & ~(size_t)255; return p; };
  unsigned short* hnb    = (unsigned short*)alloc((size_t)4096 * 512 * 2);
  unsigned short* Q1b    = (unsigned short*)alloc((size_t)4096 * 256 * 2);
  unsigned short* K1b    = (unsigned short*)alloc((size_t)4096 * 256 * 2);
  unsigned short* V1xT   = (unsigned short*)alloc((size_t)272 * 4096 * 2);
  unsigned short* CVX1Tb = (unsigned short*)alloc((size_t)272 * 4096 * 2);
  unsigned short* h1b    = (unsigned short*)alloc((size_t)4096 * 256 * 2);
  unsigned short* Q2b    = (unsigned short*)alloc((size_t)4096 * 64 * 2);
  unsigned short* K2b    = (unsigned short*)alloc((size_t)4096 * 64 * 2);
  unsigned short* V2xT   = (unsigned short*)alloc((size_t)68 * 4096 * 2);
  unsigned short* CVX2Tb = (unsigned short*)alloc((size_t)68 * 4096 * 2);
  unsigned short* h2b    = (unsigned short*)alloc((size_t)4096 * 64 * 2);
  float*          parts  = (float*)alloc((size_t)8 * 4096 * 272 * 4);

  k_norm<<<1024, 256, 0, stream>>>(feats, hnb);

  // layer-1 projections; V produced transposed w/ per-head ones-row slots
  k_mfma<0,1,1><<<dim3(32, 2), 256, 0, stream>>>(hnb, 512, Wq1, 512, Q1b, 256, 4096, 256, 512, 0);
  k_mfma<0,1,1><<<dim3(32, 2), 256, 0, stream>>>(hnb, 512, Wk1, 512, K1b, 256, 4096, 256, 512, 0);
  k_mfma<1,0,2><<<dim3(2, 32), 256, 0, stream>>>(Wv1, 512, hnb, 512, V1xT, 4096, 256, 4096, 512, 0);
  k_fix<<<256, 256, 0, stream>>>(V1xT);

  // CVX1 = counting @ [V1|1] : split-K 8 -> transpose-reduce -> bf16 [272][4096]
  k_mfma<1,0,0><<<dim3(32, 3, 8), 256, 0, stream>>>(counting, 4096, V1xT, 4096, parts, 272,
                                                    4096, 272, 4096, (unsigned long long)4096 * 272);
  k_tred<<<272 * 4096 / 256, 256, 0, stream>>>(parts, (unsigned long long)4096 * 272, 272, 8, CVX1Tb);

  // layer-1 fused attention + merge
  k_attn<<<dim3(32, 4, 4), 256, 0, stream>>>(Q1b, K1b, 256, CVX1Tb, parts);
  k_fin2<<<4096, 256, 0, stream>>>(parts, 4, h1b, 256);

  // layer-2 projections
  k_mfma<0,1,1><<<dim3(32, 1), 256, 0, stream>>>(h1b, 256, Wq2, 256, Q2b, 64, 4096, 64, 256, 0);
  k_mfma<0,1,1><<<dim3(32, 1), 256, 0, stream>>>(h1b, 256, Wk2, 256, K2b, 64, 4096, 64, 256, 0);
  k_mfma<1,0,2><<<dim3(1, 32), 256, 0, stream>>>(Wv2, 256, h1b, 256, V2xT, 4096, 64, 4096, 256, 0);
  k_fix<<<64, 256, 0, stream>>>(V2xT);

  // CVX2
  k_mfma<1,0,0><<<dim3(32, 1, 8), 256, 0, stream>>>(counting, 4096, V2xT, 4096, parts, 80,
                                                    4096, 68, 4096, (unsigned long long)4096 * 80);
  k_tred<<<68 * 4096 / 256, 256, 0, stream>>>(parts, (unsigned long long)4096 * 80, 80, 8, CVX2Tb);

  // layer-2 fused attention + merge
  k_attn<<<dim3(32, 1, 8), 256, 0, stream>>>(Q2b, K2b, 64, CVX2Tb, parts);
  k_fin2<<<1024, 256, 0, stream>>>(parts, 8, h2b, 64);

  k_cls<<<256, 256, 0, stream>>>(h2b, Wc, bc, out);
}

// Round 4
// 234.704 us; speedup vs baseline: 6.8067x; 1.1738x over previous
//
#include <hip/hip_runtime.h>
#include <hip/hip_bf16.h>
#include <math.h>

#define NN4   4096

typedef __attribute__((ext_vector_type(8))) short short8;
typedef __attribute__((ext_vector_type(8))) unsigned short ushort8;
typedef __attribute__((ext_vector_type(4))) unsigned short ushort4v;
typedef __attribute__((ext_vector_type(4))) float f32x4;

__device__ __forceinline__ unsigned short f2b(float f) {
  union { __hip_bfloat16 h; unsigned short u; } v;
  v.h = __float2bfloat16(f);
  return v.u;
}
__device__ __forceinline__ float b2f(unsigned short s) {
  return __uint_as_float(((unsigned int)s) << 16);
}

// ---------------- row normalize (mean/std over 512, ddof=1) -> bf16 ----------------
__global__ __launch_bounds__(256) void k_norm(const float* __restrict__ x,
                                              unsigned short* __restrict__ y) {
  int row  = blockIdx.x * 4 + (threadIdx.x >> 6);
  int lane = threadIdx.x & 63;
  const float4* src = (const float4*)(x + (size_t)row * 512);
  float4 a = src[lane];
  float4 b = src[lane + 64];
  float s = a.x + a.y + a.z + a.w + b.x + b.y + b.z + b.w;
#pragma unroll
  for (int off = 32; off; off >>= 1) s += __shfl_xor(s, off);
  float mean = s * (1.0f / 512.0f);
  float ssq = 0.f, d;
  d = a.x - mean; ssq += d * d;  d = a.y - mean; ssq += d * d;
  d = a.z - mean; ssq += d * d;  d = a.w - mean; ssq += d * d;
  d = b.x - mean; ssq += d * d;  d = b.y - mean; ssq += d * d;
  d = b.z - mean; ssq += d * d;  d = b.w - mean; ssq += d * d;
#pragma unroll
  for (int off = 32; off; off >>= 1) ssq += __shfl_xor(ssq, off);
  float inv = 1.0f / (sqrtf(ssq * (1.0f / 511.0f)) + 1e-9f);
  unsigned short* dst = y + (size_t)row * 512;
  ushort4v va = (ushort4v){f2b((a.x - mean) * inv), f2b((a.y - mean) * inv),
                           f2b((a.z - mean) * inv), f2b((a.w - mean) * inv)};
  ushort4v vb = (ushort4v){f2b((b.x - mean) * inv), f2b((b.y - mean) * inv),
                           f2b((b.z - mean) * inv), f2b((b.w - mean) * inv)};
  *(ushort4v*)(dst + lane * 4)       = va;
  *(ushort4v*)(dst + 256 + lane * 4) = vb;
}

// ------------------- MFMA GEMM: C[M,N] = A[M,K] @ B[N,K]^T -------------------
// EPI: 1 = bf16 store, 2 = bf16 store row-remapped r -> r + 4*(r>>6)  (V^T build)
#define LDSP 40
template<int AF32, int BF32, int EPI>
__global__ __launch_bounds__(256) void k_mfma(
    const void* __restrict__ Ap, int lda,
    const void* __restrict__ Bp, int ldb,
    void* __restrict__ Cp, int ldc,
    int M, int N, int K) {
  __shared__ unsigned short As[128 * LDSP];
  __shared__ unsigned short Bs[128 * LDSP];
  const int tid = threadIdx.x;
  const int m0 = blockIdx.x * 128, n0 = blockIdx.y * 128;
  const int lane = tid & 63, wid = tid >> 6;
  const int wr = (wid >> 1) << 6, wc = (wid & 1) << 6;
  const int srow = tid >> 1, sk = (tid & 1) << 4;
  f32x4 acc[4][4];
#pragma unroll
  for (int i = 0; i < 4; ++i)
#pragma unroll
    for (int j = 0; j < 4; ++j) acc[i][j] = (f32x4){0.f, 0.f, 0.f, 0.f};

  for (int k0 = 0; k0 < K; k0 += 32) {
    ushort8 va0, va1, vb0, vb1;
    {
      int gr = m0 + srow;
      if (gr < M) {
        if constexpr (AF32) {
          const float* s = (const float*)Ap + (size_t)gr * lda + k0 + sk;
          float4 f0 = *(const float4*)(s);
          float4 f1 = *(const float4*)(s + 4);
          float4 f2 = *(const float4*)(s + 8);
          float4 f3 = *(const float4*)(s + 12);
          va0 = (ushort8){f2b(f0.x), f2b(f0.y), f2b(f0.z), f2b(f0.w),
                          f2b(f1.x), f2b(f1.y), f2b(f1.z), f2b(f1.w)};
          va1 = (ushort8){f2b(f2.x), f2b(f2.y), f2b(f2.z), f2b(f2.w),
                          f2b(f3.x), f2b(f3.y), f2b(f3.z), f2b(f3.w)};
        } else {
          const unsigned short* s = (const unsigned short*)Ap + (size_t)gr * lda + k0 + sk;
          va0 = *(const ushort8*)(s);
          va1 = *(const ushort8*)(s + 8);
        }
      } else { va0 = (ushort8)0; va1 = (ushort8)0; }
    }
    {
      int gr = n0 + srow;
      if (gr < N) {
        if constexpr (BF32) {
          const float* s = (const float*)Bp + (size_t)gr * ldb + k0 + sk;
          float4 f0 = *(const float4*)(s);
          float4 f1 = *(const float4*)(s + 4);
          float4 f2 = *(const float4*)(s + 8);
          float4 f3 = *(const float4*)(s + 12);
          vb0 = (ushort8){f2b(f0.x), f2b(f0.y), f2b(f0.z), f2b(f0.w),
                          f2b(f1.x), f2b(f1.y), f2b(f1.z), f2b(f1.w)};
          vb1 = (ushort8){f2b(f2.x), f2b(f2.y), f2b(f2.z), f2b(f2.w),
                          f2b(f3.x), f2b(f3.y), f2b(f3.z), f2b(f3.w)};
        } else {
          const unsigned short* s = (const unsigned short*)Bp + (size_t)gr * ldb + k0 + sk;
          vb0 = *(const ushort8*)(s);
          vb1 = *(const ushort8*)(s + 8);
        }
      } else { vb0 = (ushort8)0; vb1 = (ushort8)0; }
    }
    __syncthreads();
    *(ushort8*)&As[srow * LDSP + sk]     = va0;
    *(ushort8*)&As[srow * LDSP + sk + 8] = va1;
    *(ushort8*)&Bs[srow * LDSP + sk]     = vb0;
    *(ushort8*)&Bs[srow * LDSP + sk + 8] = vb1;
    __syncthreads();
    short8 af[4], bf[4];
#pragma unroll
    for (int i = 0; i < 4; ++i)
      af[i] = *(const short8*)&As[(wr + (i << 4) + (lane & 15)) * LDSP + ((lane >> 4) << 3)];
#pragma unroll
    for (int j = 0; j < 4; ++j)
      bf[j] = *(const short8*)&Bs[(wc + (j << 4) + (lane & 15)) * LDSP + ((lane >> 4) << 3)];
#pragma unroll
    for (int i = 0; i < 4; ++i)
#pragma unroll
      for (int j = 0; j < 4; ++j)
        acc[i][j] = __builtin_amdgcn_mfma_f32_16x16x32_bf16(af[i], bf[j], acc[i][j], 0, 0, 0);
  }

#pragma unroll
  for (int i = 0; i < 4; ++i) {
#pragma unroll
    for (int j = 0; j < 4; ++j) {
#pragma unroll
      for (int reg = 0; reg < 4; ++reg) {
        int r = m0 + wr + (i << 4) + ((lane >> 4) << 2) + reg;
        int c = n0 + wc + (j << 4) + (lane & 15);
        if (r < M && c < N) {
          float v = acc[i][j][reg];
          if constexpr (EPI == 1) {
            ((unsigned short*)Cp)[(size_t)r * ldc + c] = f2b(v);
          } else {
            int r2 = r + ((r >> 6) << 2);
            ((unsigned short*)Cp)[(size_t)r2 * ldc + c] = f2b(v);
          }
        }
      }
    }
  }
}

// ---------- merged Q/K projection: grid.y low half -> (Bq,Cq), high half -> (Bk,Ck) ----------
__global__ __launch_bounds__(256) void k_proj2(
    const unsigned short* __restrict__ Ap, int lda,
    const float* __restrict__ Bq, const float* __restrict__ Bk, int ldb,
    unsigned short* __restrict__ Cq, unsigned short* __restrict__ Ck, int ldc,
    int M, int N, int K) {
  __shared__ unsigned short As[128 * LDSP];
  __shared__ unsigned short Bs[128 * LDSP];
  const int tid = threadIdx.x;
  const int half = gridDim.y >> 1;
  const int isK = blockIdx.y >= half;
  const float* Bp = isK ? Bk : Bq;
  unsigned short* Cp = isK ? Ck : Cq;
  const int m0 = blockIdx.x * 128, n0 = (isK ? blockIdx.y - half : blockIdx.y) * 128;
  const int lane = tid & 63, wid = tid >> 6;
  const int wr = (wid >> 1) << 6, wc = (wid & 1) << 6;
  const int srow = tid >> 1, sk = (tid & 1) << 4;
  f32x4 acc[4][4];
#pragma unroll
  for (int i = 0; i < 4; ++i)
#pragma unroll
    for (int j = 0; j < 4; ++j) acc[i][j] = (f32x4){0.f, 0.f, 0.f, 0.f};

  for (int k0 = 0; k0 < K; k0 += 32) {
    ushort8 va0, va1, vb0, vb1;
    {
      const unsigned short* s = Ap + (size_t)(m0 + srow) * lda + k0 + sk;
      va0 = *(const ushort8*)(s);
      va1 = *(const ushort8*)(s + 8);
    }
    {
      int gr = n0 + srow;
      if (gr < N) {
        const float* s = Bp + (size_t)gr * ldb + k0 + sk;
        float4 f0 = *(const float4*)(s);
        float4 f1 = *(const float4*)(s + 4);
        float4 f2 = *(const float4*)(s + 8);
        float4 f3 = *(const float4*)(s + 12);
        vb0 = (ushort8){f2b(f0.x), f2b(f0.y), f2b(f0.z), f2b(f0.w),
                        f2b(f1.x), f2b(f1.y), f2b(f1.z), f2b(f1.w)};
        vb1 = (ushort8){f2b(f2.x), f2b(f2.y), f2b(f2.z), f2b(f2.w),
                        f2b(f3.x), f2b(f3.y), f2b(f3.z), f2b(f3.w)};
      } else { vb0 = (ushort8)0; vb1 = (ushort8)0; }
    }
    __syncthreads();
    *(ushort8*)&As[srow * LDSP + sk]     = va0;
    *(ushort8*)&As[srow * LDSP + sk + 8] = va1;
    *(ushort8*)&Bs[srow * LDSP + sk]     = vb0;
    *(ushort8*)&Bs[srow * LDSP + sk + 8] = vb1;
    __syncthreads();
    short8 af[4], bf[4];
#pragma unroll
    for (int i = 0; i < 4; ++i)
      af[i] = *(const short8*)&As[(wr + (i << 4) + (lane & 15)) * LDSP + ((lane >> 4) << 3)];
#pragma unroll
    for (int j = 0; j < 4; ++j)
      bf[j] = *(const short8*)&Bs[(wc + (j << 4) + (lane & 15)) * LDSP + ((lane >> 4) << 3)];
#pragma unroll
    for (int i = 0; i < 4; ++i)
#pragma unroll
      for (int j = 0; j < 4; ++j)
        acc[i][j] = __builtin_amdgcn_mfma_f32_16x16x32_bf16(af[i], bf[j], acc[i][j], 0, 0, 0);
  }
#pragma unroll
  for (int i = 0; i < 4; ++i)
#pragma unroll
    for (int j = 0; j < 4; ++j)
#pragma unroll
      for (int reg = 0; reg < 4; ++reg) {
        int r = m0 + wr + (i << 4) + ((lane >> 4) << 2) + reg;
        int c = n0 + wc + (j << 4) + (lane & 15);
        if (c < N) Cp[(size_t)r * ldc + c] = f2b(acc[i][j][reg]);
      }
}

// --------- CVX: Cf[4096][NF*16] += counting[128-tile][kslice] @ Bt[row][k]^T (atomic) ---------
// grid (32 m-blocks, 8 k-slices). Bt = V^T bf16 [brows][4096] incl. ones rows.
template<int NF>
__global__ __launch_bounds__(256, 2) void k_cvx(
    const float* __restrict__ cnt,
    const unsigned short* __restrict__ Bt, int brows,
    float* __restrict__ Cf) {
  constexpr int LD = NF * 16;
  constexpr int NCH = NF * 64;                 // ushort8 chunks per k-step
  constexpr int NIT = (NCH + 255) / 256;
  __shared__ unsigned short As[128 * 40];
  __shared__ unsigned short Bs[LD * 40];
  const int tid = threadIdx.x, lane = tid & 63, wid = tid >> 6;
  const int hi = lane >> 4, lo = lane & 15;
  const int m0 = blockIdx.x * 128;
  const int kbeg = blockIdx.y * 512, kend = kbeg + 512;
  const int arow = tid >> 1, ak = (tid & 1) << 4;
  f32x4 acc[2][NF];
#pragma unroll
  for (int i = 0; i < 2; ++i)
#pragma unroll
    for (int j = 0; j < NF; ++j) acc[i][j] = (f32x4){0.f, 0.f, 0.f, 0.f};

  for (int k0 = kbeg; k0 < kend; k0 += 32) {
    const float* s = cnt + (size_t)(m0 + arow) * 4096 + k0 + ak;
    float4 f0 = *(const float4*)(s);
    float4 f1 = *(const float4*)(s + 4);
    float4 f2 = *(const float4*)(s + 8);
    float4 f3 = *(const float4*)(s + 12);
    ushort8 va0 = (ushort8){f2b(f0.x), f2b(f0.y), f2b(f0.z), f2b(f0.w),
                            f2b(f1.x), f2b(f1.y), f2b(f1.z), f2b(f1.w)};
    ushort8 va1 = (ushort8){f2b(f2.x), f2b(f2.y), f2b(f2.z), f2b(f2.w),
                            f2b(f3.x), f2b(f3.y), f2b(f3.z), f2b(f3.w)};
    ushort8 vb[NIT];
#pragma unroll
    for (int i = 0; i < NIT; ++i) {
      int c = tid + i * 256;
      vb[i] = (ushort8)0;
      if (c < NCH) {
        int row = c >> 2, kc = (c & 3) << 3;
        if (row < brows) vb[i] = *(const ushort8*)(Bt + (size_t)row * 4096 + k0 + kc);
      }
    }
    __syncthreads();
    *(ushort8*)&As[arow * 40 + ak]     = va0;
    *(ushort8*)&As[arow * 40 + ak + 8] = va1;
#pragma unroll
    for (int i = 0; i < NIT; ++i) {
      int c = tid + i * 256;
      if (c < NCH) {
        int row = c >> 2, kc = (c & 3) << 3;
        *(ushort8*)&Bs[row * 40 + kc] = vb[i];
      }
    }
    __syncthreads();
    short8 af0 = *(const short8*)&As[(32 * wid + lo) * 40 + hi * 8];
    short8 af1 = *(const short8*)&As[(32 * wid + 16 + lo) * 40 + hi * 8];
#pragma unroll
    for (int j = 0; j < NF; ++j) {
      short8 bf = *(const short8*)&Bs[(16 * j + lo) * 40 + hi * 8];
      acc[0][j] = __builtin_amdgcn_mfma_f32_16x16x32_bf16(af0, bf, acc[0][j], 0, 0, 0);
      acc[1][j] = __builtin_amdgcn_mfma_f32_16x16x32_bf16(af1, bf, acc[1][j], 0, 0, 0);
    }
    __syncthreads();
  }
#pragma unroll
  for (int i = 0; i < 2; ++i)
#pragma unroll
    for (int j = 0; j < NF; ++j)
#pragma unroll
      for (int reg = 0; reg < 4; ++reg) {
        int r = m0 + 32 * wid + 16 * i + 4 * hi + reg;
        int c = 16 * j + lo;
        atomicAdd(&Cf[(size_t)r * LD + c], acc[i][j][reg]);
      }
}

// ---------- transpose + bf16 convert: in[4096][ldin] f32 -> out[orow][4096] bf16 ----------
__global__ __launch_bounds__(256) void k_tredT(const float* __restrict__ in, int ldin,
                                               unsigned short* __restrict__ out, int orow) {
  __shared__ float t[64][65];
  int n0 = blockIdx.x << 6, d0 = blockIdx.y << 6;
  int c = threadIdx.x & 63, r4 = threadIdx.x >> 6;
#pragma unroll
  for (int i = 0; i < 16; ++i) {
    int r = r4 + (i << 2);
    float v = 0.f;
    if (d0 + c < ldin) v = in[(size_t)(n0 + r) * ldin + d0 + c];
    t[c][r] = v;
  }
  __syncthreads();
#pragma unroll
  for (int i = 0; i < 16; ++i) {
    int r = r4 + (i << 2);
    if (d0 + r < orow)
      out[(size_t)(d0 + r) * 4096 + n0 + c] = f2b(t[r][c]);
  }
}

// ---------------- fused GKAT attention: num = exp(Q K^T / 8) @ CVX^T ----------------
__global__ __launch_bounds__(256, 2) void k_attn(
    const unsigned short* __restrict__ Qg, const unsigned short* __restrict__ Kg,
    int ldqk, const unsigned short* __restrict__ CVg,
    float* __restrict__ parts) {
  __shared__ unsigned short Ks[128 * 72];
  __shared__ unsigned short Cs[80 * 136];
  __shared__ unsigned short Es[128 * 136];
  const int tid = threadIdx.x, lane = tid & 63, wid = tid >> 6;
  const int hi = lane >> 4, lo = lane & 15;
  const int qb = blockIdx.x, h = blockIdx.y, sl = blockIdx.z;
  const int n0 = qb * 128;
  const int MS = 4096 / gridDim.z;
  const int m0beg = sl * MS;
  const int wr = (wid >> 1) << 6, wc = (wid & 1) << 6;

  short8 qf[4][2];
  const unsigned short* Qh = Qg + (size_t)h * 64;
#pragma unroll
  for (int j = 0; j < 4; ++j)
#pragma unroll
    for (int t = 0; t < 2; ++t)
      qf[j][t] = *(const short8*)(Qh + (size_t)(n0 + wc + 16 * j + lo) * ldqk + t * 32 + hi * 8);

  const unsigned short* CVh = CVg + (size_t)h * 68 * NN4;
  const unsigned short* Kh  = Kg + (size_t)h * 64;

  f32x4 accn[2][5];
#pragma unroll
  for (int i = 0; i < 2; ++i)
#pragma unroll
    for (int j = 0; j < 5; ++j) accn[i][j] = (f32x4){0.f, 0.f, 0.f, 0.f};

  for (int mt = 0; mt < MS; mt += 128) {
    const int m0 = m0beg + mt;
    __syncthreads();
    {
      const int row = tid >> 1, half = (tid & 1) << 5;
      const unsigned short* src = Kh + (size_t)(m0 + row) * ldqk + half;
      ushort8 v0 = *(const ushort8*)(src);
      ushort8 v1 = *(const ushort8*)(src + 8);
      ushort8 v2 = *(const ushort8*)(src + 16);
      ushort8 v3 = *(const ushort8*)(src + 24);
      unsigned short* dp = &Ks[row * 72 + half];
      *(ushort8*)(dp) = v0; *(ushort8*)(dp + 8) = v1;
      *(ushort8*)(dp + 16) = v2; *(ushort8*)(dp + 24) = v3;
    }
#pragma unroll
    for (int k = 0; k < 5; ++k) {
      int c = tid + k * 256;
      int row = c >> 4, col = (c & 15) << 3;
      ushort8 v = (ushort8)0;
      if (row < 68) v = *(const ushort8*)(CVh + (size_t)row * NN4 + m0 + col);
      *(ushort8*)&Cs[row * 136 + col] = v;
    }
    __syncthreads();
    f32x4 s[4][4];
#pragma unroll
    for (int i = 0; i < 4; ++i)
#pragma unroll
      for (int j = 0; j < 4; ++j) s[i][j] = (f32x4){0.f, 0.f, 0.f, 0.f};
    short8 kf[4][2];
#pragma unroll
    for (int i = 0; i < 4; ++i)
#pragma unroll
      for (int t = 0; t < 2; ++t)
        kf[i][t] = *(const short8*)&Ks[(wr + 16 * i + lo) * 72 + t * 32 + hi * 8];
#pragma unroll
    for (int t = 0; t < 2; ++t)
#pragma unroll
      for (int i = 0; i < 4; ++i)
#pragma unroll
        for (int j = 0; j < 4; ++j)
          s[i][j] = __builtin_amdgcn_mfma_f32_16x16x32_bf16(kf[i][t], qf[j][t], s[i][j], 0, 0, 0);
#pragma unroll
    for (int i = 0; i < 4; ++i)
#pragma unroll
      for (int j = 0; j < 4; ++j) {
        unsigned int u0 = (unsigned int)f2b(__expf(s[i][j][0] * 0.125f)) |
                          ((unsigned int)f2b(__expf(s[i][j][1] * 0.125f)) << 16);
        unsigned int u1 = (unsigned int)f2b(__expf(s[i][j][2] * 0.125f)) |
                          ((unsigned int)f2b(__expf(s[i][j][3] * 0.125f)) << 16);
        unsigned long long pk = (unsigned long long)u0 | ((unsigned long long)u1 << 32);
        *(unsigned long long*)&Es[(size_t)(wc + 16 * j + lo) * 136 + wr + 16 * i + 4 * hi] = pk;
      }
    __syncthreads();
#pragma unroll
    for (int t2 = 0; t2 < 4; ++t2) {
      short8 ea0 = *(const short8*)&Es[(32 * wid + lo) * 136 + t2 * 32 + hi * 8];
      short8 ea1 = *(const short8*)&Es[(32 * wid + 16 + lo) * 136 + t2 * 32 + hi * 8];
      short8 cb[5];
#pragma unroll
      for (int j2 = 0; j2 < 5; ++j2)
        cb[j2] = *(const short8*)&Cs[(16 * j2 + lo) * 136 + t2 * 32 + hi * 8];
#pragma unroll
      for (int j2 = 0; j2 < 5; ++j2) {
        accn[0][j2] = __builtin_amdgcn_mfma_f32_16x16x32_bf16(ea0, cb[j2], accn[0][j2], 0, 0, 0);
        accn[1][j2] = __builtin_amdgcn_mfma_f32_16x16x32_bf16(ea1, cb[j2], accn[1][j2], 0, 0, 0);
      }
    }
  }
  float* P = parts + (((size_t)h * gridDim.x + qb) * gridDim.z + sl) * (128 * 80);
#pragma unroll
  for (int i2 = 0; i2 < 2; ++i2)
#pragma unroll
    for (int j2 = 0; j2 < 5; ++j2)
#pragma unroll
      for (int reg = 0; reg < 4; ++reg) {
        int r = 32 * wid + 16 * i2 + 4 * hi + reg;
        int c = 16 * j2 + lo;
        P[(size_t)r * 80 + c] = accn[i2][j2][reg];
      }
}

// ---------- merge slices: x = num/(den+1e-9), elu, bf16 store ----------
__global__ void k_fin2(const float* __restrict__ parts, int nsl,
                       unsigned short* __restrict__ hb, int ldh) {
  int idx = blockIdx.x * 256 + threadIdx.x;
  int d = idx & 63, r = (idx >> 6) & 4095, h = idx >> 18;
  size_t b0 = ((size_t)(h * 32 + (r >> 7)) * nsl) * 10240 + (size_t)(r & 127) * 80;
  float nm = 0.f, dn = 0.f;
  for (int sl = 0; sl < nsl; ++sl) {
    const float* p = parts + b0 + (size_t)sl * 10240;
    nm += p[d]; dn += p[64];
  }
  float x = nm / (dn + 1e-9f);
  x = x > 0.f ? x : expm1f(x);
  hb[(size_t)r * ldh + h * 64 + d] = f2b(x);
}

// ---------- set ones/zero pad rows of V^T buffers: row h*68+64+j = (j==0) ----------
__global__ void k_fix(unsigned short* __restrict__ v) {
  int idx = blockIdx.x * 256 + threadIdx.x;
  int h = idx >> 14, j = (idx >> 12) & 3, n = idx & 4095;
  v[(size_t)(h * 68 + 64 + j) * NN4 + n] = (j == 0) ? 0x3F80 : 0;
}

// ---------- classifier ----------
__global__ void k_cls(const unsigned short* __restrict__ h2, const float* __restrict__ Wc,
                      const float* __restrict__ bc, float* __restrict__ out) {
  int idx = blockIdx.x * 256 + threadIdx.x;
  int r = idx >> 4, cl = idx & 15;
  if (cl >= 10) return;
  float s = 0.f;
  for (int k = 0; k < 64; ++k) s += b2f(h2[(size_t)r * 64 + k]) * Wc[cl * 64 + k];
  out[(size_t)r * 10 + cl] = s + bc[cl];
}

extern "C" void kernel_launch(void* const* d_in, const int* in_sizes, int n_in,
                              void* d_out, int out_size, void* d_ws, size_t ws_size,
                              hipStream_t stream) {
  (void)in_sizes; (void)n_in; (void)out_size; (void)ws_size;
  const float* feats    = (const float*)d_in[0];
  const float* counting = (const float*)d_in[1];
  const float* Wq1 = (const float*)d_in[2];
  const float* Wk1 = (const float*)d_in[3];
  const float* Wv1 = (const float*)d_in[4];
  const float* Wq2 = (const float*)d_in[5];
  const float* Wk2 = (const float*)d_in[6];
  const float* Wv2 = (const float*)d_in[7];
  const float* Wc  = (const float*)d_in[8];
  const float* bc  = (const float*)d_in[9];
  float* out = (float*)d_out;

  char* w = (char*)d_ws;
  size_t off = 0;
  auto alloc = [&](size_t bytes) { void* p = w + off; off += (bytes + 255) & ~(size_t)255; return p; };
  unsigned short* hnb    = (unsigned short*)alloc((size_t)4096 * 512 * 2);
  unsigned short* Q1b    = (unsigned short*)alloc((size_t)4096 * 256 * 2);
  unsigned short* K1b    = (unsigned short*)alloc((size_t)4096 * 256 * 2);
  unsigned short* V1xT   = (unsigned short*)alloc((size_t)272 * 4096 * 2);
  unsigned short* CVX1Tb = (unsigned short*)alloc((size_t)272 * 4096 * 2);
  unsigned short* h1b    = (unsigned short*)alloc((size_t)4096 * 256 * 2);
  unsigned short* Q2b    = (unsigned short*)alloc((size_t)4096 * 64 * 2);
  unsigned short* K2b    = (unsigned short*)alloc((size_t)4096 * 64 * 2);
  unsigned short* V2xT   = (unsigned short*)alloc((size_t)68 * 4096 * 2);
  unsigned short* CVX2Tb = (unsigned short*)alloc((size_t)68 * 4096 * 2);
  unsigned short* h2b    = (unsigned short*)alloc((size_t)4096 * 64 * 2);
  float*          CVXf1  = (float*)alloc((size_t)4096 * 272 * 4);
  float*          CVXf2  = (float*)alloc((size_t)4096 * 80 * 4);
  float*          parts  = (float*)alloc((size_t)4 * 32 * 4 * 128 * 80 * 4);  // 21 MB

  k_norm<<<1024, 256, 0, stream>>>(feats, hnb);

  // layer-1 projections
  k_proj2<<<dim3(32, 4), 256, 0, stream>>>(hnb, 512, Wq1, Wk1, 512, Q1b, K1b, 256, 4096, 256, 512);
  k_mfma<1, 0, 2><<<dim3(2, 32), 256, 0, stream>>>(Wv1, 512, hnb, 512, V1xT, 4096, 256, 4096, 512);
  k_fix<<<256, 256, 0, stream>>>(V1xT);

  // CVX1 = counting @ [V1|1]  (single counting pass, atomic f32)
  hipMemsetAsync(CVXf1, 0, (size_t)4096 * 272 * 4, stream);
  k_cvx<17><<<dim3(32, 8), 256, 0, stream>>>(counting, V1xT, 272, CVXf1);
  k_tredT<<<dim3(64, 5), 256, 0, stream>>>(CVXf1, 272, CVX1Tb, 272);

  // layer-1 fused attention + merge
  k_attn<<<dim3(32, 4, 4), 256, 0, stream>>>(Q1b, K1b, 256, CVX1Tb, parts);
  k_fin2<<<4096, 256, 0, stream>>>(parts, 4, h1b, 256);

  // layer-2 projections
  k_proj2<<<dim3(32, 2), 256, 0, stream>>>(h1b, 256, Wq2, Wk2, 256, Q2b, K2b, 64, 4096, 64, 256);
  k_mfma<1, 0, 2><<<dim3(1, 32), 256, 0, stream>>>(Wv2, 256, h1b, 256, V2xT, 4096, 64, 4096, 256);
  k_fix<<<64, 256, 0, stream>>>(V2xT);

  // CVX2
  hipMemsetAsync(CVXf2, 0, (size_t)4096 * 80 * 4, stream);
  k_cvx<5><<<dim3(32, 8), 256, 0, stream>>>(counting, V2xT, 68, CVXf2);
  k_tredT<<<dim3(64, 2), 256, 0, stream>>>(CVXf2, 80, CVX2Tb, 68);

  // layer-2 fused attention + merge
  k_attn<<<dim3(32, 1, 8), 256, 0, stream>>>(Q2b, K2b, 64, CVX2Tb, parts);
  k_fin2<<<1024, 256, 0, stream>>>(parts, 8, h2b, 64);

  k_cls<<<256, 256, 0, stream>>>(h2b, Wc, bc, out);
}